// Round 3
// baseline (337.830 us; speedup 1.0000x reference)
//
#include <hip/hip_runtime.h>
#include <math.h>

#define L_MAX 2048
#define BATCH 64
#define DIM   256
#define CCH   512

// ws layout (floats):
#define HQ_OFF   0          // 64*256  = 16384
#define WF_OFF   16384      // 3*256   = 768
#define SUMS_OFF 17152      // 64*32 (one cache line per b) = 2048
#define HARD_OFF 19200      // 2048*64 = 131072
#define PART_OFF 150272     // 32*64*256 = 524288
#define SUMS_STRIDE 32

__device__ __forceinline__ float fast_tanh(float x) {
    float ax = fabsf(x);
    float e  = __expf(2.0f * ax);                       // inf for big ax -> r=1
    float r  = 1.0f - 2.0f * __builtin_amdgcn_rcpf(e + 1.0f);
    return copysignf(r, x);
}

// Kernel A: hq[b][d] = sum_k ht_query[b][k]*W_query[d][k]
//           wf[j][d] = sum_c W_conv[c][0][j]*W_att_past[d][c]
//           block 0 additionally zeroes sums[] (replaces a memset dispatch).
__global__ __launch_bounds__(256) void prep_kernel(
    const float* __restrict__ ht_query, const float* __restrict__ W_query,
    const float* __restrict__ W_conv,   const float* __restrict__ W_att_past,
    float* __restrict__ hq, float* __restrict__ wf, float* __restrict__ sums) {
    int t   = threadIdx.x;
    int blk = blockIdx.x;
    if (blk == 0 && t < BATCH) sums[t * SUMS_STRIDE] = 0.f;
    __shared__ float q[DIM];
    if (blk < BATCH) {
        q[t] = ht_query[blk * DIM + t];
        __syncthreads();
        const float4* wrow = (const float4*)(W_query + t * DIM);
        float acc = 0.f;
        #pragma unroll 8
        for (int k = 0; k < DIM / 4; k++) {
            float4 wv = wrow[k];
            acc += q[4*k] * wv.x + q[4*k+1] * wv.y + q[4*k+2] * wv.z + q[4*k+3] * wv.w;
        }
        hq[blk * DIM + t] = acc;
    } else {
        int j = blk - BATCH;
        const float4* wrow = (const float4*)(W_att_past + t * CCH);
        float acc = 0.f;
        #pragma unroll 8
        for (int c = 0; c < CCH / 4; c++) {
            float4 wv = wrow[c];
            acc += W_conv[(4*c  ) * 3 + j] * wv.x + W_conv[(4*c+1) * 3 + j] * wv.y
                 + W_conv[(4*c+2) * 3 + j] * wv.z + W_conv[(4*c+3) * 3 + j] * wv.w;
        }
        wf[j * DIM + t] = acc;
    }
}

// Fused kernel B: score + hard + partial ct, one pass.
// block = (b, chunk of 64 l's); 4 waves x 16 rows. Butterfly reduce leaves the
// score in ALL lanes, so each lane immediately accumulates h * ctx_val row.
// One padded atomic per block for Z_b; partials to part[] (no ct atomics).
__global__ __launch_bounds__(256) void fused_kernel(
    const float* __restrict__ ctx_key, const float* __restrict__ ctx_val,
    const float* __restrict__ ctx_mask, const float* __restrict__ att_past,
    const float* __restrict__ hq, const float* __restrict__ wf,
    const float* __restrict__ b_att_past, const float* __restrict__ W_attn,
    const float* __restrict__ b_attn,
    float* __restrict__ hard_raw, float* __restrict__ sums,
    float* __restrict__ part) {
    int b     = blockIdx.x & 63;
    int chunk = blockIdx.x >> 6;
    int w     = threadIdx.x >> 6;
    int lane  = threadIdx.x & 63;
    int d0    = lane << 2;
    int l0    = chunk * 64 + w * 16;

    float4 hq4 = *(const float4*)(hq + b * DIM + d0);
    float4 bp  = *(const float4*)(b_att_past + d0);
    hq4.x += bp.x; hq4.y += bp.y; hq4.z += bp.z; hq4.w += bp.w;
    float4 w0  = *(const float4*)(wf + d0);
    float4 w1  = *(const float4*)(wf + DIM + d0);
    float4 w2  = *(const float4*)(wf + 2 * DIM + d0);
    float4 wa  = *(const float4*)(W_attn + d0);
    float battn = b_attn[0];
    const float* apb = att_past + b * L_MAX;

    float cnt = 0.f;
    float4 acc = make_float4(0.f, 0.f, 0.f, 0.f);

    for (int i = 0; i < 16; i += 4) {
        float4 k4[4];
        float am[4], a0[4], a1[4];
        #pragma unroll
        for (int j = 0; j < 4; j++) {
            int l = l0 + i + j;
            k4[j] = *(const float4*)(ctx_key + (size_t)(l * BATCH + b) * DIM + d0);
            am[j] = (l > 0)         ? apb[l - 1] : 0.f;
            a0[j] = apb[l];
            a1[j] = (l < L_MAX - 1) ? apb[l + 1] : 0.f;
        }
        float p[4];
        #pragma unroll
        for (int j = 0; j < 4; j++) {
            float x0 = k4[j].x + hq4.x + am[j] * w0.x + a0[j] * w1.x + a1[j] * w2.x;
            float x1 = k4[j].y + hq4.y + am[j] * w0.y + a0[j] * w1.y + a1[j] * w2.y;
            float x2 = k4[j].z + hq4.z + am[j] * w0.z + a0[j] * w1.z + a1[j] * w2.z;
            float x3 = k4[j].w + hq4.w + am[j] * w0.w + a0[j] * w1.w + a1[j] * w2.w;
            p[j] = fast_tanh(x0) * wa.x + fast_tanh(x1) * wa.y +
                   fast_tanh(x2) * wa.z + fast_tanh(x3) * wa.w;
        }
        #pragma unroll
        for (int off = 32; off > 0; off >>= 1) {
            p[0] += __shfl_xor(p[0], off, 64);
            p[1] += __shfl_xor(p[1], off, 64);
            p[2] += __shfl_xor(p[2], off, 64);
            p[3] += __shfl_xor(p[3], off, 64);
        }
        // p[j] now holds the full dot in every lane.
        #pragma unroll
        for (int j = 0; j < 4; j++) {
            int l = l0 + i + j;
            float h = (p[j] + battn >= 0.f) ? ctx_mask[l * BATCH + b] : 0.f;
            if (lane == 0) hard_raw[l * BATCH + b] = h;
            cnt += h;
            if (h != 0.f) {               // wave-uniform branch
                float4 v = *(const float4*)(ctx_val + (size_t)(l * BATCH + b) * DIM + d0);
                acc.x += v.x * h; acc.y += v.y * h;
                acc.z += v.z * h; acc.w += v.w * h;
            }
        }
    }

    __shared__ float red[4 * DIM];
    *(float4*)(red + w * DIM + d0) = acc;
    __shared__ float c4[4];
    if (lane == 0) c4[w] = cnt;
    __syncthreads();
    int d = threadIdx.x;
    float s = red[d] + red[DIM + d] + red[2 * DIM + d] + red[3 * DIM + d];
    part[(size_t)(chunk * BATCH + b) * DIM + d] = s;
    if (threadIdx.x == 0)
        atomicAdd(&sums[b * SUMS_STRIDE], c4[0] + c4[1] + c4[2] + c4[3]);
}

// Tail: blocks 0..63  -> ct[b][d] = (sum_chunk part) / (Z_b+1e-10)
//       blocks 64..191 -> out_hard[l][b] = hard_raw[l][b] / (Z_b+1e-10)
__global__ __launch_bounds__(256) void tail_kernel(
    const float* __restrict__ part, const float* __restrict__ hard_raw,
    const float* __restrict__ sums,
    float* __restrict__ ct, float* __restrict__ out_hard) {
    if (blockIdx.x < BATCH) {
        int b = blockIdx.x;
        int d = threadIdx.x;
        float s = 0.f;
        #pragma unroll 8
        for (int c = 0; c < 32; c++)
            s += part[(size_t)(c * BATCH + b) * DIM + d];
        float invZ = 1.0f / (sums[b * SUMS_STRIDE] + 1e-10f);
        ct[b * DIM + d] = s * invZ;
    } else {
        int i = (blockIdx.x - BATCH) * 256 + threadIdx.x;   // 4 elems each
        float4 h = *(const float4*)(hard_raw + (size_t)i * 4);
        int b0 = (i * 4) & 63;
        float4 o;
        o.x = h.x / (sums[(b0 + 0) * SUMS_STRIDE] + 1e-10f);
        o.y = h.y / (sums[(b0 + 1) * SUMS_STRIDE] + 1e-10f);
        o.z = h.z / (sums[(b0 + 2) * SUMS_STRIDE] + 1e-10f);
        o.w = h.w / (sums[(b0 + 3) * SUMS_STRIDE] + 1e-10f);
        *(float4*)(out_hard + (size_t)i * 4) = o;
    }
}

extern "C" void kernel_launch(void* const* d_in, const int* in_sizes, int n_in,
                              void* d_out, int out_size, void* d_ws, size_t ws_size,
                              hipStream_t stream) {
    const float* ctx_val    = (const float*)d_in[0];
    const float* ctx_key    = (const float*)d_in[1];
    const float* ctx_mask   = (const float*)d_in[2];
    const float* att_past   = (const float*)d_in[3];
    const float* ht_query   = (const float*)d_in[4];
    const float* W_conv     = (const float*)d_in[5];
    const float* W_query    = (const float*)d_in[6];
    const float* W_att_past = (const float*)d_in[7];
    const float* b_att_past = (const float*)d_in[8];
    const float* W_attn     = (const float*)d_in[9];
    const float* b_attn     = (const float*)d_in[10];

    float* ws   = (float*)d_ws;
    float* hq   = ws + HQ_OFF;
    float* wf   = ws + WF_OFF;
    float* sums = ws + SUMS_OFF;
    float* hard = ws + HARD_OFF;
    float* part = ws + PART_OFF;

    float* out_ct   = (float*)d_out;                 // (64,256)
    float* out_hard = (float*)d_out + BATCH * DIM;   // (2048,64)

    prep_kernel<<<BATCH + 3, 256, 0, stream>>>(
        ht_query, W_query, W_conv, W_att_past, hq, wf, sums);

    fused_kernel<<<BATCH * 32, 256, 0, stream>>>(
        ctx_key, ctx_val, ctx_mask, att_past, hq, wf, b_att_past, W_attn, b_attn,
        hard, sums, part);

    tail_kernel<<<BATCH + 128, 256, 0, stream>>>(part, hard, sums, out_ct, out_hard);
}

// Round 4
// 331.298 us; speedup vs baseline: 1.0197x; 1.0197x over previous
//
#include <hip/hip_runtime.h>
#include <math.h>

#define L_MAX 2048
#define BATCH 64
#define DIM   256
#define CCH   512
#define ROWSTRIDE (BATCH * DIM)   // floats between consecutive l at fixed b

// ws layout (floats):
#define HQ_OFF   0          // 64*256  = 16384
#define WF_OFF   16384      // 3*256   = 768
#define SUMS_OFF 17152      // 64*32 (one cache line per b) = 2048
#define HARD_OFF 19200      // 2048*64 = 131072
#define PART_OFF 150272     // 32*64*256 = 524288
#define SUMS_STRIDE 32

__device__ __forceinline__ float fast_tanh(float x) {
    float ax = fabsf(x);
    float e  = __expf(2.0f * ax);                       // inf for big ax -> r=1
    float r  = 1.0f - 2.0f * __builtin_amdgcn_rcpf(e + 1.0f);
    return copysignf(r, x);
}

// Kernel A: hq[b][d] = sum_k ht_query[b][k]*W_query[d][k]
//           wf[j][d] = sum_c W_conv[c][0][j]*W_att_past[d][c]
//           block 0 additionally zeroes sums[].
__global__ __launch_bounds__(256) void prep_kernel(
    const float* __restrict__ ht_query, const float* __restrict__ W_query,
    const float* __restrict__ W_conv,   const float* __restrict__ W_att_past,
    float* __restrict__ hq, float* __restrict__ wf, float* __restrict__ sums) {
    int t   = threadIdx.x;
    int blk = blockIdx.x;
    if (blk == 0 && t < BATCH) sums[t * SUMS_STRIDE] = 0.f;
    __shared__ float q[DIM];
    if (blk < BATCH) {
        q[t] = ht_query[blk * DIM + t];
        __syncthreads();
        const float4* wrow = (const float4*)(W_query + t * DIM);
        float acc = 0.f;
        #pragma unroll 8
        for (int k = 0; k < DIM / 4; k++) {
            float4 wv = wrow[k];
            acc += q[4*k] * wv.x + q[4*k+1] * wv.y + q[4*k+2] * wv.z + q[4*k+3] * wv.w;
        }
        hq[blk * DIM + t] = acc;
    } else {
        int j = blk - BATCH;
        const float4* wrow = (const float4*)(W_att_past + t * CCH);
        float acc = 0.f;
        #pragma unroll 8
        for (int c = 0; c < CCH / 4; c++) {
            float4 wv = wrow[c];
            acc += W_conv[(4*c  ) * 3 + j] * wv.x + W_conv[(4*c+1) * 3 + j] * wv.y
                 + W_conv[(4*c+2) * 3 + j] * wv.z + W_conv[(4*c+3) * 3 + j] * wv.w;
        }
        wf[j * DIM + t] = acc;
    }
}

// Fused kernel: score + hard + partial ct, one pass, burst-streaming.
// block = (b, chunk of 64 l's); 4 waves x 16 rows (2 groups of 8).
// Per group: ALL 8 key + 8 val float4 loads issued unconditionally up front
// (16 KB/wave in flight), scores computed, butterfly-reduced (result in all
// lanes), then val rows scaled by h and accumulated. att_past hoisted into
// registers once per wave. One padded atomic per block for Z_b.
__global__ __launch_bounds__(256) void fused_kernel(
    const float* __restrict__ ctx_key, const float* __restrict__ ctx_val,
    const float* __restrict__ ctx_mask, const float* __restrict__ att_past,
    const float* __restrict__ hq, const float* __restrict__ wf,
    const float* __restrict__ b_att_past, const float* __restrict__ W_attn,
    const float* __restrict__ b_attn,
    float* __restrict__ hard_raw, float* __restrict__ sums,
    float* __restrict__ part) {
    int b     = blockIdx.x & 63;
    int chunk = blockIdx.x >> 6;
    int w     = threadIdx.x >> 6;
    int lane  = threadIdx.x & 63;
    int d0    = lane << 2;
    int l0    = chunk * 64 + w * 16;

    float4 hq4 = *(const float4*)(hq + b * DIM + d0);
    float4 bp  = *(const float4*)(b_att_past + d0);
    hq4.x += bp.x; hq4.y += bp.y; hq4.z += bp.z; hq4.w += bp.w;
    float4 w0  = *(const float4*)(wf + d0);
    float4 w1  = *(const float4*)(wf + DIM + d0);
    float4 w2  = *(const float4*)(wf + 2 * DIM + d0);
    float4 wa  = *(const float4*)(W_attn + d0);
    float battn = b_attn[0];
    const float* apb = att_past + b * L_MAX;

    // Hoist att_past window [l0-1, l0+16] into registers: ap[i] = apb[l0-1+i]
    float ap[18];
    {
        float4 t0 = *(const float4*)(apb + l0);
        float4 t1 = *(const float4*)(apb + l0 + 4);
        float4 t2 = *(const float4*)(apb + l0 + 8);
        float4 t3 = *(const float4*)(apb + l0 + 12);
        ap[1]=t0.x; ap[2]=t0.y; ap[3]=t0.z; ap[4]=t0.w;
        ap[5]=t1.x; ap[6]=t1.y; ap[7]=t1.z; ap[8]=t1.w;
        ap[9]=t2.x; ap[10]=t2.y; ap[11]=t2.z; ap[12]=t2.w;
        ap[13]=t3.x; ap[14]=t3.y; ap[15]=t3.z; ap[16]=t3.w;
        ap[0]  = (l0 > 0)              ? apb[l0 - 1]  : 0.f;
        ap[17] = (l0 + 16 < L_MAX)     ? apb[l0 + 16] : 0.f;
    }

    const float* key_base = ctx_key + (size_t)(l0 * BATCH + b) * DIM + d0;
    const float* val_base = ctx_val + (size_t)(l0 * BATCH + b) * DIM + d0;

    float cnt = 0.f;
    float4 acc = make_float4(0.f, 0.f, 0.f, 0.f);

    #pragma unroll
    for (int g = 0; g < 2; g++) {
        // ---- burst: 16 independent float4 loads + 8 mask scalars ----
        float4 k8[8], v8[8];
        float m8[8];
        #pragma unroll
        for (int j = 0; j < 8; j++)
            k8[j] = *(const float4*)(key_base + (size_t)(g * 8 + j) * ROWSTRIDE);
        #pragma unroll
        for (int j = 0; j < 8; j++)
            v8[j] = *(const float4*)(val_base + (size_t)(g * 8 + j) * ROWSTRIDE);
        #pragma unroll
        for (int j = 0; j < 8; j++)
            m8[j] = ctx_mask[(l0 + g * 8 + j) * BATCH + b];

        // ---- scores ----
        float p[8];
        #pragma unroll
        for (int j = 0; j < 8; j++) {
            float am = ap[g * 8 + j];
            float a0 = ap[g * 8 + j + 1];
            float a1 = ap[g * 8 + j + 2];
            float x0 = k8[j].x + hq4.x + am * w0.x + a0 * w1.x + a1 * w2.x;
            float x1 = k8[j].y + hq4.y + am * w0.y + a0 * w1.y + a1 * w2.y;
            float x2 = k8[j].z + hq4.z + am * w0.z + a0 * w1.z + a1 * w2.z;
            float x3 = k8[j].w + hq4.w + am * w0.w + a0 * w1.w + a1 * w2.w;
            p[j] = fast_tanh(x0) * wa.x + fast_tanh(x1) * wa.y +
                   fast_tanh(x2) * wa.z + fast_tanh(x3) * wa.w;
        }
        #pragma unroll
        for (int off = 32; off > 0; off >>= 1) {
            #pragma unroll
            for (int j = 0; j < 8; j++)
                p[j] += __shfl_xor(p[j], off, 64);
        }
        // p[j] holds the full dot in every lane.
        #pragma unroll
        for (int j = 0; j < 8; j++) {
            int l = l0 + g * 8 + j;
            float h = (p[j] + battn >= 0.f) ? m8[j] : 0.f;
            if (lane == 0) hard_raw[l * BATCH + b] = h;
            cnt += h;
            acc.x += v8[j].x * h; acc.y += v8[j].y * h;
            acc.z += v8[j].z * h; acc.w += v8[j].w * h;
        }
    }

    __shared__ float red[4 * DIM];
    *(float4*)(red + w * DIM + d0) = acc;
    __shared__ float c4[4];
    if (lane == 0) c4[w] = cnt;
    __syncthreads();
    int d = threadIdx.x;
    float s = red[d] + red[DIM + d] + red[2 * DIM + d] + red[3 * DIM + d];
    part[(size_t)(chunk * BATCH + b) * DIM + d] = s;
    if (threadIdx.x == 0)
        atomicAdd(&sums[b * SUMS_STRIDE], c4[0] + c4[1] + c4[2] + c4[3]);
}

// Tail: blocks 0..63   -> ct[b][d] = (sum_chunk part) / (Z_b+1e-10)
//       blocks 64..191 -> out_hard[l][b] = hard_raw[l][b] / (Z_b+1e-10)
__global__ __launch_bounds__(256) void tail_kernel(
    const float* __restrict__ part, const float* __restrict__ hard_raw,
    const float* __restrict__ sums,
    float* __restrict__ ct, float* __restrict__ out_hard) {
    if (blockIdx.x < BATCH) {
        int b = blockIdx.x;
        int d = threadIdx.x;
        float s = 0.f;
        #pragma unroll 8
        for (int c = 0; c < 32; c++)
            s += part[(size_t)(c * BATCH + b) * DIM + d];
        float invZ = 1.0f / (sums[b * SUMS_STRIDE] + 1e-10f);
        ct[b * DIM + d] = s * invZ;
    } else {
        int i = (blockIdx.x - BATCH) * 256 + threadIdx.x;   // 4 elems each
        float4 h = *(const float4*)(hard_raw + (size_t)i * 4);
        int b0 = (i * 4) & 63;
        float4 o;
        o.x = h.x / (sums[(b0 + 0) * SUMS_STRIDE] + 1e-10f);
        o.y = h.y / (sums[(b0 + 1) * SUMS_STRIDE] + 1e-10f);
        o.z = h.z / (sums[(b0 + 2) * SUMS_STRIDE] + 1e-10f);
        o.w = h.w / (sums[(b0 + 3) * SUMS_STRIDE] + 1e-10f);
        *(float4*)(out_hard + (size_t)i * 4) = o;
    }
}

extern "C" void kernel_launch(void* const* d_in, const int* in_sizes, int n_in,
                              void* d_out, int out_size, void* d_ws, size_t ws_size,
                              hipStream_t stream) {
    const float* ctx_val    = (const float*)d_in[0];
    const float* ctx_key    = (const float*)d_in[1];
    const float* ctx_mask   = (const float*)d_in[2];
    const float* att_past   = (const float*)d_in[3];
    const float* ht_query   = (const float*)d_in[4];
    const float* W_conv     = (const float*)d_in[5];
    const float* W_query    = (const float*)d_in[6];
    const float* W_att_past = (const float*)d_in[7];
    const float* b_att_past = (const float*)d_in[8];
    const float* W_attn     = (const float*)d_in[9];
    const float* b_attn     = (const float*)d_in[10];

    float* ws   = (float*)d_ws;
    float* hq   = ws + HQ_OFF;
    float* wf   = ws + WF_OFF;
    float* sums = ws + SUMS_OFF;
    float* hard = ws + HARD_OFF;
    float* part = ws + PART_OFF;

    float* out_ct   = (float*)d_out;                 // (64,256)
    float* out_hard = (float*)d_out + BATCH * DIM;   // (2048,64)

    prep_kernel<<<BATCH + 3, 256, 0, stream>>>(
        ht_query, W_query, W_conv, W_att_past, hq, wf, sums);

    fused_kernel<<<BATCH * 32, 256, 0, stream>>>(
        ctx_key, ctx_val, ctx_mask, att_past, hq, wf, b_att_past, W_attn, b_attn,
        hard, sums, part);

    tail_kernel<<<BATCH + 128, 256, 0, stream>>>(part, hard, sums, out_ct, out_hard);
}

// Round 5
// 324.235 us; speedup vs baseline: 1.0419x; 1.0218x over previous
//
#include <hip/hip_runtime.h>
#include <math.h>

#define L_MAX 2048
#define BATCH 64
#define DIM   256
#define CCH   512
#define ROWSTRIDE (BATCH * DIM)   // floats between consecutive l at fixed b

// ws layout (floats):
#define HQ_OFF   0          // 64*256  = 16384
#define WF_OFF   16384      // 3*256   = 768
#define SUMS_OFF 17152      // 64*32 (one cache line per b) = 2048
#define HARD_OFF 19200      // 2048*64 = 131072
#define PART_OFF 150272     // 32*64*256 = 524288
#define SUMS_STRIDE 32

__device__ __forceinline__ float fast_tanh(float x) {
    float ax = fabsf(x);
    float e  = __expf(2.0f * ax);                       // inf for big ax -> r=1
    float r  = 1.0f - 2.0f * __builtin_amdgcn_rcpf(e + 1.0f);
    return copysignf(r, x);
}

// Kernel A: hq[b][d] = sum_k ht_query[b][k]*W_query[d][k]
//           wf[j][d] = sum_c W_conv[c][0][j]*W_att_past[d][c]
//           block 0 additionally zeroes sums[].
__global__ __launch_bounds__(256) void prep_kernel(
    const float* __restrict__ ht_query, const float* __restrict__ W_query,
    const float* __restrict__ W_conv,   const float* __restrict__ W_att_past,
    float* __restrict__ hq, float* __restrict__ wf, float* __restrict__ sums) {
    int t   = threadIdx.x;
    int blk = blockIdx.x;
    if (blk == 0 && t < BATCH) sums[t * SUMS_STRIDE] = 0.f;
    __shared__ float q[DIM];
    if (blk < BATCH) {
        q[t] = ht_query[blk * DIM + t];
        __syncthreads();
        const float4* wrow = (const float4*)(W_query + t * DIM);
        float acc = 0.f;
        #pragma unroll 8
        for (int k = 0; k < DIM / 4; k++) {
            float4 wv = wrow[k];
            acc += q[4*k] * wv.x + q[4*k+1] * wv.y + q[4*k+2] * wv.z + q[4*k+3] * wv.w;
        }
        hq[blk * DIM + t] = acc;
    } else {
        int j = blk - BATCH;
        const float4* wrow = (const float4*)(W_att_past + t * CCH);
        float acc = 0.f;
        #pragma unroll 8
        for (int c = 0; c < CCH / 4; c++) {
            float4 wv = wrow[c];
            acc += W_conv[(4*c  ) * 3 + j] * wv.x + W_conv[(4*c+1) * 3 + j] * wv.y
                 + W_conv[(4*c+2) * 3 + j] * wv.z + W_conv[(4*c+3) * 3 + j] * wv.w;
        }
        wf[j * DIM + t] = acc;
    }
}

// Fused kernel: score + hard + partial ct in one pass.
// block = (b, chunk of 64 l's); 4 waves x 16 rows.
// Phase 1: ONE burst of 16 key float4 loads (16 KB/wave in flight, one drain).
// Phase 2: 16 scores, 16-way butterfly (result identical in all 64 lanes --
//          IEEE add is commutative, tree shape identical per lane).
// Phase 3: 16 val loads issued branchless back-to-back; rows with h==0 have
//          their address cndmask'ed to tile row 0 (stays in L1/L2 -> ~no HBM
//          bytes), acc += v*h zeroes the dummy contribution.
__global__ __launch_bounds__(256) void fused_kernel(
    const float* __restrict__ ctx_key, const float* __restrict__ ctx_val,
    const float* __restrict__ ctx_mask, const float* __restrict__ att_past,
    const float* __restrict__ hq, const float* __restrict__ wf,
    const float* __restrict__ b_att_past, const float* __restrict__ W_attn,
    const float* __restrict__ b_attn,
    float* __restrict__ hard_raw, float* __restrict__ sums,
    float* __restrict__ part) {
    int b     = blockIdx.x & 63;
    int chunk = blockIdx.x >> 6;
    int w     = threadIdx.x >> 6;
    int lane  = threadIdx.x & 63;
    int d0    = lane << 2;
    int l0    = chunk * 64 + w * 16;

    float4 hq4 = *(const float4*)(hq + b * DIM + d0);
    float4 bp  = *(const float4*)(b_att_past + d0);
    hq4.x += bp.x; hq4.y += bp.y; hq4.z += bp.z; hq4.w += bp.w;
    float4 w0  = *(const float4*)(wf + d0);
    float4 w1  = *(const float4*)(wf + DIM + d0);
    float4 w2  = *(const float4*)(wf + 2 * DIM + d0);
    float4 wa  = *(const float4*)(W_attn + d0);
    float battn = b_attn[0];
    const float* apb = att_past + b * L_MAX;

    // att_past window [l0-1, l0+16]: ap[i] = apb[l0-1+i]
    float ap[18];
    {
        float4 t0 = *(const float4*)(apb + l0);
        float4 t1 = *(const float4*)(apb + l0 + 4);
        float4 t2 = *(const float4*)(apb + l0 + 8);
        float4 t3 = *(const float4*)(apb + l0 + 12);
        ap[1]=t0.x; ap[2]=t0.y; ap[3]=t0.z; ap[4]=t0.w;
        ap[5]=t1.x; ap[6]=t1.y; ap[7]=t1.z; ap[8]=t1.w;
        ap[9]=t2.x; ap[10]=t2.y; ap[11]=t2.z; ap[12]=t2.w;
        ap[13]=t3.x; ap[14]=t3.y; ap[15]=t3.z; ap[16]=t3.w;
        ap[0]  = (l0 > 0)          ? apb[l0 - 1]  : 0.f;
        ap[17] = (l0 + 16 < L_MAX) ? apb[l0 + 16] : 0.f;
    }

    const float* key_base = ctx_key + (size_t)(l0 * BATCH + b) * DIM + d0;
    const float* val_base = ctx_val + (size_t)(l0 * BATCH + b) * DIM + d0;

    // ---- Phase 1: one burst of 16 key rows + 16 (scalar) mask loads ----
    float4 k16[16];
    float m16[16];
    #pragma unroll
    for (int j = 0; j < 16; j++)
        k16[j] = *(const float4*)(key_base + (size_t)j * ROWSTRIDE);
    #pragma unroll
    for (int j = 0; j < 16; j++)
        m16[j] = ctx_mask[(l0 + j) * BATCH + b];

    // ---- Phase 2: 16 scores + butterfly ----
    float p[16];
    #pragma unroll
    for (int j = 0; j < 16; j++) {
        float am = ap[j], a0 = ap[j + 1], a1 = ap[j + 2];
        float x0 = k16[j].x + hq4.x + am * w0.x + a0 * w1.x + a1 * w2.x;
        float x1 = k16[j].y + hq4.y + am * w0.y + a0 * w1.y + a1 * w2.y;
        float x2 = k16[j].z + hq4.z + am * w0.z + a0 * w1.z + a1 * w2.z;
        float x3 = k16[j].w + hq4.w + am * w0.w + a0 * w1.w + a1 * w2.w;
        p[j] = fast_tanh(x0) * wa.x + fast_tanh(x1) * wa.y +
               fast_tanh(x2) * wa.z + fast_tanh(x3) * wa.w;
    }
    #pragma unroll
    for (int off = 32; off > 0; off >>= 1) {
        #pragma unroll
        for (int j = 0; j < 16; j++)
            p[j] += __shfl_xor(p[j], off, 64);
    }

    float h[16];
    float cnt = 0.f;
    #pragma unroll
    for (int j = 0; j < 16; j++) {
        h[j] = (p[j] + battn >= 0.f) ? m16[j] : 0.f;
        cnt += h[j];
    }
    if (lane == 0) {
        #pragma unroll
        for (int j = 0; j < 16; j++)
            hard_raw[(l0 + j) * BATCH + b] = h[j];
    }

    // ---- Phase 3: branchless val burst; h==0 rows read tile row 0 ----
    float4 acc = make_float4(0.f, 0.f, 0.f, 0.f);
    float4 v16[16];
    #pragma unroll
    for (int j = 0; j < 16; j++) {
        size_t off = (h[j] != 0.f) ? (size_t)j * ROWSTRIDE : 0;
        v16[j] = *(const float4*)(val_base + off);
    }
    #pragma unroll
    for (int j = 0; j < 16; j++) {
        acc.x += v16[j].x * h[j]; acc.y += v16[j].y * h[j];
        acc.z += v16[j].z * h[j]; acc.w += v16[j].w * h[j];
    }

    __shared__ float red[4 * DIM];
    *(float4*)(red + w * DIM + d0) = acc;
    __shared__ float c4[4];
    if (lane == 0) c4[w] = cnt;
    __syncthreads();
    int d = threadIdx.x;
    float s = red[d] + red[DIM + d] + red[2 * DIM + d] + red[3 * DIM + d];
    part[(size_t)(chunk * BATCH + b) * DIM + d] = s;
    if (threadIdx.x == 0)
        atomicAdd(&sums[b * SUMS_STRIDE], c4[0] + c4[1] + c4[2] + c4[3]);
}

// Tail: blocks 0..63   -> ct[b][d] = (sum_chunk part) / (Z_b+1e-10)
//       blocks 64..191 -> out_hard[l][b] = hard_raw[l][b] / (Z_b+1e-10)
__global__ __launch_bounds__(256) void tail_kernel(
    const float* __restrict__ part, const float* __restrict__ hard_raw,
    const float* __restrict__ sums,
    float* __restrict__ ct, float* __restrict__ out_hard) {
    if (blockIdx.x < BATCH) {
        int b = blockIdx.x;
        int d = threadIdx.x;
        float s = 0.f;
        #pragma unroll 8
        for (int c = 0; c < 32; c++)
            s += part[(size_t)(c * BATCH + b) * DIM + d];
        float invZ = 1.0f / (sums[b * SUMS_STRIDE] + 1e-10f);
        ct[b * DIM + d] = s * invZ;
    } else {
        int i = (blockIdx.x - BATCH) * 256 + threadIdx.x;   // 4 elems each
        float4 h = *(const float4*)(hard_raw + (size_t)i * 4);
        int b0 = (i * 4) & 63;
        float4 o;
        o.x = h.x / (sums[(b0 + 0) * SUMS_STRIDE] + 1e-10f);
        o.y = h.y / (sums[(b0 + 1) * SUMS_STRIDE] + 1e-10f);
        o.z = h.z / (sums[(b0 + 2) * SUMS_STRIDE] + 1e-10f);
        o.w = h.w / (sums[(b0 + 3) * SUMS_STRIDE] + 1e-10f);
        *(float4*)(out_hard + (size_t)i * 4) = o;
    }
}

extern "C" void kernel_launch(void* const* d_in, const int* in_sizes, int n_in,
                              void* d_out, int out_size, void* d_ws, size_t ws_size,
                              hipStream_t stream) {
    const float* ctx_val    = (const float*)d_in[0];
    const float* ctx_key    = (const float*)d_in[1];
    const float* ctx_mask   = (const float*)d_in[2];
    const float* att_past   = (const float*)d_in[3];
    const float* ht_query   = (const float*)d_in[4];
    const float* W_conv     = (const float*)d_in[5];
    const float* W_query    = (const float*)d_in[6];
    const float* W_att_past = (const float*)d_in[7];
    const float* b_att_past = (const float*)d_in[8];
    const float* W_attn     = (const float*)d_in[9];
    const float* b_attn     = (const float*)d_in[10];

    float* ws   = (float*)d_ws;
    float* hq   = ws + HQ_OFF;
    float* wf   = ws + WF_OFF;
    float* sums = ws + SUMS_OFF;
    float* hard = ws + HARD_OFF;
    float* part = ws + PART_OFF;

    float* out_ct   = (float*)d_out;                 // (64,256)
    float* out_hard = (float*)d_out + BATCH * DIM;   // (2048,64)

    prep_kernel<<<BATCH + 3, 256, 0, stream>>>(
        ht_query, W_query, W_conv, W_att_past, hq, wf, sums);

    fused_kernel<<<BATCH * 32, 256, 0, stream>>>(
        ctx_key, ctx_val, ctx_mask, att_past, hq, wf, b_att_past, W_attn, b_attn,
        hard, sums, part);

    tail_kernel<<<BATCH + 128, 256, 0, stream>>>(part, hard, sums, out_ct, out_hard);
}